// Round 6
// baseline (529.553 us; speedup 1.0000x reference)
//
#include <hip/hip_runtime.h>
#include <cstdint>
#include <cstddef>

typedef _Float16 f16_t;
typedef f16_t f16x8 __attribute__((ext_vector_type(8)));
typedef float  floatx4 __attribute__((ext_vector_type(4)));

#define S_LEN 2048
#define DIM_  4096
#define NH    32
#define NKV   8
#define HD    128
#define KV_DIM (NKV * HD)        // 1024
#define QLD   (DIM_ + 2 * KV_DIM) // 6144: fused QKV row stride

// round-to-nearest-even onto the bf16 grid, result stays fp32.
__device__ __forceinline__ float bf16r(float x) {
    uint32_t u = __float_as_uint(x);
    u = (u + 0x7fffu + ((u >> 16) & 1u)) & 0xffff0000u;
    return __uint_as_float(u);
}

// async global->LDS, 16B per lane (lane-contiguous LDS dest required)
__device__ __forceinline__ void gload_lds16(const f16_t* g, f16_t* l) {
    __builtin_amdgcn_global_load_lds(
        (const __attribute__((address_space(1))) void*)g,
        (__attribute__((address_space(3))) void*)l, 16, 0, 0);
}

// ---------------------------------------------------------------------------
// fp32 -> bf16-grid -> fp16 (lossless embed), 8 elements / thread
// ---------------------------------------------------------------------------
__global__ void f32_to_f16_kernel(const float* __restrict__ in,
                                  f16_t* __restrict__ out, int n) {
    int i = (blockIdx.x * blockDim.x + threadIdx.x) * 8;
    if (i >= n) return;
    float4 a = *(const float4*)(in + i);
    float4 b = *(const float4*)(in + i + 4);
    f16x8 o;
    o[0] = (f16_t)bf16r(a.x); o[1] = (f16_t)bf16r(a.y);
    o[2] = (f16_t)bf16r(a.z); o[3] = (f16_t)bf16r(a.w);
    o[4] = (f16_t)bf16r(b.x); o[5] = (f16_t)bf16r(b.y);
    o[6] = (f16_t)bf16r(b.z); o[7] = (f16_t)bf16r(b.w);
    *(f16x8*)(out + i) = o;
}

// ---------------------------------------------------------------------------
// all 4 weight transposes in ONE kernel (fp32 -> bf16 grid -> fp16).
// ---------------------------------------------------------------------------
__global__ void transpose_weights_kernel(const float* __restrict__ wq,
                                         const float* __restrict__ wk,
                                         const float* __restrict__ wv,
                                         const float* __restrict__ wo,
                                         f16_t* __restrict__ wqkvT,
                                         f16_t* __restrict__ woT) {
    __shared__ float tile[32][33];
    int bid = blockIdx.x;
    const float* in; f16_t* out; int C;
    if (bid < 16384)      { in = wq; out = wqkvT;                          C = 4096; }
    else if (bid < 20480) { bid -= 16384; in = wk; out = wqkvT + (size_t)4096 * 4096; C = 1024; }
    else if (bid < 24576) { bid -= 20480; in = wv; out = wqkvT + (size_t)5120 * 4096; C = 1024; }
    else                  { bid -= 24576; in = wo; out = woT;              C = 4096; }
    int gpr = C / 32;
    int bx = (bid % gpr) * 32;
    int by = (bid / gpr) * 32;
    int tx = threadIdx.x, ty = threadIdx.y;
#pragma unroll
    for (int i = 0; i < 4; i++) {
        int r = ty + i * 8;
        tile[r][tx] = in[(size_t)(by + r) * C + bx + tx];
    }
    __syncthreads();
#pragma unroll
    for (int i = 0; i < 4; i++) {
        int r = ty + i * 8;
        out[(size_t)(bx + r) * 4096 + by + tx] = (f16_t)bf16r(tile[tx][r]);
    }
}

// ---------------------------------------------------------------------------
// generic fp16 transpose with strides: in [R][C] (ldi) -> out [C][R] (ldo)
// ---------------------------------------------------------------------------
__global__ void transpose_f16_kernel(const f16_t* __restrict__ in,
                                     f16_t* __restrict__ out,
                                     int ldi, int ldo) {
    __shared__ float tile[32][33];
    int bx = blockIdx.x * 32;
    int by = blockIdx.y * 32;
    int tx = threadIdx.x, ty = threadIdx.y;
#pragma unroll
    for (int i = 0; i < 4; i++) {
        int r = ty + i * 8;
        tile[r][tx] = (float)in[(size_t)(by + r) * ldi + bx + tx];
    }
    __syncthreads();
#pragma unroll
    for (int i = 0; i < 4; i++) {
        int r = ty + i * 8;
        out[(size_t)(bx + r) * ldo + by + tx] = (f16_t)tile[tx][r];
    }
}

// ---------------------------------------------------------------------------
// RoPE in-place over QKVb cols 0..5119 (Q and K), bf16-grid cos/sin, fp32
// math; Q additionally pre-scaled by 1/sqrt(HD). grid (5, 2048), block 128.
// ---------------------------------------------------------------------------
__global__ void rope_qk_kernel(f16_t* __restrict__ QKV,
                               const float* __restrict__ fcos,
                               const float* __restrict__ fsin) {
    int c8 = (blockIdx.x * blockDim.x + threadIdx.x) * 8;
    int row = blockIdx.y;
    f16_t* p = QKV + (size_t)row * QLD + c8;
    f16x8 v = *(f16x8*)p;
    const float* cr = fcos + row * 64 + ((c8 & 127) >> 1);
    const float* sr = fsin + row * 64 + ((c8 & 127) >> 1);
    const float sc = (c8 < DIM_) ? 0.08838834764831845f : 1.0f;
#pragma unroll
    for (int u = 0; u < 4; u++) {
        float cc = bf16r(cr[u]), ss = bf16r(sr[u]);
        float re = (float)v[2 * u], im = (float)v[2 * u + 1];
        v[2 * u]     = (f16_t)((re * cc - im * ss) * sc);
        v[2 * u + 1] = (f16_t)((re * ss + im * cc) * sc);
    }
    *(f16x8*)p = v;
}

// ---------------------------------------------------------------------------
// 8-phase fp16 GEMM (T3+T4+T2+T5 port): C[M][N] = A[M][K] @ BT[N][K]^T
// BK=64, double-buffered LDS, 8 waves (2M x 4N), per-wave BM/2 x 64.
// Per K-tile: 4 phases {ds_read quadrant frags -> barrier -> lgkmcnt(0) ->
// setprio(1) MFMA quadrant setprio(0) -> barrier}. All 4 half-tiles of t+1
// staged at phase 0 of tile t (into buf (t+1)&1, disjoint from read buf),
// single vmcnt(0) drain at phase-3 end (~3 phases after issue: near-free).
// st_16x32 swizzle: lds_byte = L ^ (((L>>9)&1)<<5), applied via
// inverse-swizzled GLOBAL source (linear gload_lds dest) + same XOR on reads.
// ---------------------------------------------------------------------------
template <int BM, int BN, typename OutT>
__global__ __launch_bounds__(512, 2) void gemm_8p_kernel(
        const f16_t* __restrict__ A, const f16_t* __restrict__ BT,
        OutT* __restrict__ C, int M, int N, int K, int nbx) {
    constexpr int BK = 64;
    constexpr int MT = BM / 32;            // per-wave M frags (WM=2)
    constexpr int NT = BN / 64;            // per-wave N frags (WN=4) == 4
    constexpr int MH = MT / 2;             // frags per phase-half
    constexpr int AHALF = (BM / 2) * 64;   // f16 per A half region
    constexpr int BHALF = (BN / 2) * 64;
    constexpr int BUF   = (BM + BN) * 64;  // f16 per buffer
    constexpr int AJ = BM / 128;           // 8KB issues per A half
    constexpr int BJ = BN / 128;

    __shared__ f16_t lds[2 * BUF];

    const int tid  = threadIdx.x;
    const int lane = tid & 63;
    const int wave = tid >> 6;
    const int quad = lane >> 4;
    const int l16  = lane & 15;
    const int wmi  = wave >> 2;   // 0..1
    const int wni  = wave & 3;    // 0..3

    const int nwg = gridDim.x;
    const int swz = (blockIdx.x & 7) * (nwg >> 3) + (blockIdx.x >> 3);
    const int m0 = (swz / nbx) * BM;
    const int n0 = (swz % nbx) * BN;

    // precomputed per-thread staging pointers (inverse-swizzled global col)
    const f16_t* srcA[2][AJ]; int dA[2][AJ];
    const f16_t* srcB[2][BJ]; int dB[2][BJ];
#pragma unroll
    for (int h = 0; h < 2; h++)
#pragma unroll
        for (int j = 0; j < AJ; j++) {
            int L = j * 8192 + tid * 16;
            int r = L >> 7;
            int c = ((L & 127) ^ (((L >> 9) & 1) << 5)) >> 1;
            srcA[h][j] = A + (size_t)(m0 + h * (BM / 2) + r) * K + c;
            dA[h][j] = h * AHALF + (L >> 1);
        }
#pragma unroll
    for (int h = 0; h < 2; h++)
#pragma unroll
        for (int j = 0; j < BJ; j++) {
            int L = j * 8192 + tid * 16;
            int r = L >> 7;
            int c = ((L & 127) ^ (((L >> 9) & 1) << 5)) >> 1;
            srcB[h][j] = BT + (size_t)(n0 + h * (BN / 2) + r) * K + c;
            dB[h][j] = 2 * AHALF + h * BHALF + (L >> 1);
        }

    auto stage_all = [&](int tt) {
        f16_t* base = lds + (tt & 1) * BUF;
        const int k0 = tt * BK;
#pragma unroll
        for (int h = 0; h < 2; h++)
#pragma unroll
            for (int j = 0; j < AJ; j++)
                gload_lds16(srcA[h][j] + k0, base + dA[h][j]);
#pragma unroll
        for (int h = 0; h < 2; h++)
#pragma unroll
            for (int j = 0; j < BJ; j++)
                gload_lds16(srcB[h][j] + k0, base + dB[h][j]);
    };

    floatx4 acc[MT][NT] = {};
    const int ntk = K / BK;

    // prologue: tile 0 staged + drained
    stage_all(0);
    asm volatile("s_waitcnt vmcnt(0)" ::: "memory");
    __builtin_amdgcn_s_barrier();
    __builtin_amdgcn_sched_barrier(0);

#define PHASE(mh, ks, STAGE, DRAIN)                                           \
    {                                                                         \
        STAGE                                                                 \
        _Pragma("unroll")                                                     \
        for (int i = 0; i < MH; i++) {                                        \
            int r_ = ((mh) * MH + i) * 16 + l16;                              \
            int cb_ = (((ks) * 64) + quad * 16) ^ (((r_ >> 2) & 1) << 5);     \
            af[i] = *(const f16x8*)(Ab + r_ * 64 + (cb_ >> 1));               \
        }                                                                     \
        if ((mh) == 0) {                                                      \
            _Pragma("unroll")                                                 \
            for (int nt = 0; nt < NT; nt++) {                                 \
                int rb_ = (wni & 1) * 64 + nt * 16 + l16;                     \
                int cb_ = (((ks) * 64) + quad * 16) ^ (((rb_ >> 2) & 1) << 5);\
                bf[nt] = *(const f16x8*)(Bb + rb_ * 64 + (cb_ >> 1));         \
            }                                                                 \
        }                                                                     \
        __builtin_amdgcn_sched_barrier(0);                                    \
        __builtin_amdgcn_s_barrier();                                         \
        asm volatile("s_waitcnt lgkmcnt(0)" ::: "memory");                    \
        __builtin_amdgcn_sched_barrier(0);                                    \
        __builtin_amdgcn_s_setprio(1);                                        \
        _Pragma("unroll")                                                     \
        for (int i = 0; i < MH; i++)                                          \
            _Pragma("unroll")                                                 \
            for (int nt = 0; nt < NT; nt++)                                   \
                acc[(mh) * MH + i][nt] =                                      \
                    __builtin_amdgcn_mfma_f32_16x16x32_f16(                   \
                        af[i], bf[nt], acc[(mh) * MH + i][nt], 0, 0, 0);      \
        __builtin_amdgcn_s_setprio(0);                                        \
        DRAIN                                                                 \
        __builtin_amdgcn_sched_barrier(0);                                    \
        __builtin_amdgcn_s_barrier();                                         \
        __builtin_amdgcn_sched_barrier(0);                                    \
    }

    for (int t = 0; t < ntk; ++t) {
        const f16_t* Ab = lds + (t & 1) * BUF + wmi * AHALF;
        const f16_t* Bb = lds + (t & 1) * BUF + 2 * AHALF + (wni >> 1) * BHALF;
        const bool pre = (t + 1 < ntk);
        f16x8 af[MH], bf[NT];

        PHASE(0, 0, if (pre) stage_all(t + 1);, )
        PHASE(1, 0, , )
        PHASE(0, 1, , )
        PHASE(1, 1, ,
              if (pre) { asm volatile("s_waitcnt vmcnt(0)" ::: "memory"); })
    }
#undef PHASE

#pragma unroll
    for (int mt = 0; mt < MT; mt++)
#pragma unroll
        for (int nt = 0; nt < NT; nt++)
#pragma unroll
            for (int rg = 0; rg < 4; rg++) {
                int row = m0 + wmi * (BM / 2) + mt * 16 + quad * 4 + rg;
                int col = n0 + wni * 64 + nt * 16 + l16;
                C[(size_t)row * N + col] = (OutT)acc[mt][nt][rg];
            }
}

// ---------------------------------------------------------------------------
// Flash attention, causal. Q/K pre-roped (Q pre-scaled by 1/sqrt(HD)).
// (unchanged from round 5)
// ---------------------------------------------------------------------------
__global__ __launch_bounds__(512) void attn_kernel(
        const f16_t* __restrict__ QKV, const f16_t* __restrict__ Vt,
        f16_t* __restrict__ O) {
    constexpr int BK = 64;
    __shared__ f16_t Ks[BK * HD];
    __shared__ f16_t Vs[HD * BK];
    __shared__ f16_t Ps[8][16][72];

    const int tid  = threadIdx.x;
    const int lane = tid & 63;
    const int wave = tid >> 6;
    const int quad = lane >> 4;
    const int l16  = lane & 15;

    const int bid = blockIdx.x;
    const int h   = bid & 31;
    const int g   = bid >> 5;
    const int qt  = (g < 8) ? g : 23 - g;
    const int q0  = qt * 128;
    const int hkv = h >> 2;

    const int qrow = q0 + wave * 16 + l16;
    const f16_t* Qg = QKV + (size_t)qrow * QLD + h * HD;
    f16x8 qf[4];
#pragma unroll
    for (int c = 0; c < 4; c++) qf[c] = *(const f16x8*)(Qg + c * 32 + quad * 8);

    floatx4 o_acc[8] = {};
    floatx4 l_acc = {0.f, 0.f, 0.f, 0.f};
    float m_run[4];
#pragma unroll
    for (int i = 0; i < 4; i++) m_run[i] = -1e30f;

    f16x8 ones;
#pragma unroll
    for (int i = 0; i < 8; i++) ones[i] = (f16_t)1.0f;

    const int q_lo = q0 + wave * 16;
    const int q_hi = q_lo + 15;
    const int ntiles = q0 / BK + 2;

    const int rK = tid >> 4;
    const int cK = (((tid & 15) * 16) ^ ((rK & 7) << 4)) >> 1;
    const f16_t* pK = QKV + (size_t)rK * QLD + DIM_ + hkv * HD + cK;
    const int rV = tid >> 3;
    const int cV = (((tid & 7) * 16) ^ ((rV & 7) << 4)) >> 1;
    const f16_t* pV = Vt + (size_t)hkv * HD * S_LEN + (size_t)rV * S_LEN + cV;
    f16_t* KsD0 = Ks + tid * 8;  f16_t* KsD1 = KsD0 + 4096;
    f16_t* VsD0 = Vs + tid * 8;  f16_t* VsD1 = VsD0 + 4096;

    for (int t = 0; t < ntiles; t++) {
        const int k0 = t * BK;

        gload_lds16(pK + (size_t)k0 * QLD, KsD0);
        gload_lds16(pK + (size_t)(k0 + 32) * QLD, KsD1);
        gload_lds16(pV + k0, VsD0);
        gload_lds16(pV + k0 + (size_t)64 * S_LEN, VsD1);
        asm volatile("s_waitcnt vmcnt(0)" ::: "memory");
        __syncthreads();

        if (k0 <= q_hi) {
            floatx4 sc4[4] = {};
#pragma unroll
            for (int nt = 0; nt < 4; nt++) {
                const int r = nt * 16 + l16;
#pragma unroll
                for (int ks = 0; ks < 4; ks++) {
                    int cb = (ks * 64 + quad * 16) ^ ((r & 7) << 4);
                    f16x8 kf = *(const f16x8*)(Ks + r * 128 + (cb >> 1));
                    sc4[nt] = __builtin_amdgcn_mfma_f32_16x16x32_f16(qf[ks], kf, sc4[nt], 0, 0, 0);
                }
            }

            if ((k0 + BK - 1) > q_lo) {
#pragma unroll
                for (int nt = 0; nt < 4; nt++)
#pragma unroll
                    for (int rg = 0; rg < 4; rg++) {
                        int qg = q_lo + quad * 4 + rg;
                        int kg = k0 + nt * 16 + l16;
                        if (kg > qg) sc4[nt][rg] = -1e30f;
                    }
            }

            float m_t[4];
#pragma unroll
            for (int rg = 0; rg < 4; rg++) {
                float m = fmaxf(fmaxf(sc4[0][rg], sc4[1][rg]), fmaxf(sc4[2][rg], sc4[3][rg]));
#pragma unroll
                for (int off = 8; off >= 1; off >>= 1)
                    m = fmaxf(m, __shfl_xor(m, off, 64));
                m_t[rg] = m;
            }
            int grow = (m_t[0] > m_run[0] + 8.f) | (m_t[1] > m_run[1] + 8.f) |
                       (m_t[2] > m_run[2] + 8.f) | (m_t[3] > m_run[3] + 8.f);
            if (__any(grow)) {
                float alpha[4];
#pragma unroll
                for (int rg = 0; rg < 4; rg++) {
                    float mn = fmaxf(m_run[rg], m_t[rg]);
                    alpha[rg] = __expf(m_run[rg] - mn);
                    m_run[rg] = mn;
                }
#pragma unroll
                for (int dt = 0; dt < 8; dt++)
#pragma unroll
                    for (int rg = 0; rg < 4; rg++) o_acc[dt][rg] *= alpha[rg];
#pragma unroll
                for (int rg = 0; rg < 4; rg++) l_acc[rg] *= alpha[rg];
            }

#pragma unroll
            for (int nt = 0; nt < 4; nt++)
#pragma unroll
                for (int rg = 0; rg < 4; rg++)
                    Ps[wave][quad * 4 + rg][nt * 16 + l16] =
                        (f16_t)__expf(sc4[nt][rg] - m_run[rg]);
            asm volatile("s_waitcnt lgkmcnt(0)" ::: "memory");
            __builtin_amdgcn_sched_barrier(0);

#pragma unroll
            for (int ks = 0; ks < 2; ks++) {
                f16x8 pf = *(const f16x8*)&Ps[wave][l16][ks * 32 + quad * 8];
                l_acc = __builtin_amdgcn_mfma_f32_16x16x32_f16(pf, ones, l_acc, 0, 0, 0);
#pragma unroll
                for (int dt = 0; dt < 8; dt++) {
                    const int r = dt * 16 + l16;
                    int cb = (ks * 64 + quad * 16) ^ ((r & 7) << 4);
                    f16x8 vf = *(const f16x8*)(Vs + r * 64 + (cb >> 1));
                    o_acc[dt] = __builtin_amdgcn_mfma_f32_16x16x32_f16(pf, vf, o_acc[dt], 0, 0, 0);
                }
            }
        }
        __syncthreads();
    }

#pragma unroll
    for (int rg = 0; rg < 4; rg++) {
        float inv_l = 1.0f / l_acc[rg];
#pragma unroll
        for (int dt = 0; dt < 8; dt++) {
            int row = q0 + wave * 16 + quad * 4 + rg;
            int col = h * HD + dt * 16 + l16;
            O[(size_t)row * (NH * HD) + col] = (f16_t)(o_acc[dt][rg] * inv_l);
        }
    }
}

// ---------------------------------------------------------------------------
// launch
// ---------------------------------------------------------------------------
extern "C" void kernel_launch(void* const* d_in, const int* in_sizes, int n_in,
                              void* d_out, int out_size, void* d_ws, size_t ws_size,
                              hipStream_t stream) {
    const float* x    = (const float*)d_in[0];
    const float* wq   = (const float*)d_in[1];
    const float* wk   = (const float*)d_in[2];
    const float* wv   = (const float*)d_in[3];
    const float* wo   = (const float*)d_in[4];
    const float* fcos = (const float*)d_in[5];
    const float* fsin = (const float*)d_in[6];
    float* out = (float*)d_out;

    char* ws = (char*)d_ws;
    constexpr size_t MB = 1024 * 1024;
    f16_t* xb    = (f16_t*)(ws + 0 * MB);     // 16 MB  [2048][4096]
    f16_t* wqkvT = (f16_t*)(ws + 16 * MB);    // 48 MB  [6144][4096]
    f16_t* woT   = (f16_t*)(ws + 64 * MB);    // 32 MB  [4096][4096]
    f16_t* QKVb  = (f16_t*)(ws + 96 * MB);    // 24 MB  [2048][6144]
    f16_t* Vt    = (f16_t*)(ws + 120 * MB);   //  4 MB  [8][128][2048]
    f16_t* attnb = (f16_t*)(ws + 124 * MB);   // 16 MB  [2048][4096]

    // 1. convert x; transpose-convert all weights (bf16 grid)
    f32_to_f16_kernel<<<S_LEN * DIM_ / 8 / 256, 256, 0, stream>>>(x, xb, S_LEN * DIM_);
    transpose_weights_kernel<<<40960, dim3(32, 8), 0, stream>>>(wq, wk, wv, wo, wqkvT, woT);

    // 2. fused QKV projection: 256x256 tiles -> 8 x 24 = 192 blocks
    gemm_8p_kernel<256, 256, f16_t><<<192, 512, 0, stream>>>(
        xb, wqkvT, QKVb, S_LEN, QLD, DIM_, QLD / 256);

    // 3. RoPE Q+K in-place (Q pre-scaled); V^T transpose
    rope_qk_kernel<<<dim3(5, S_LEN), 128, 0, stream>>>(QKVb, fcos, fsin);
    transpose_f16_kernel<<<dim3(KV_DIM / 32, S_LEN / 32), dim3(32, 8), 0, stream>>>(
        QKVb + 5120, Vt, QLD, S_LEN);

    // 4. causal flash attention
    attn_kernel<<<512, 512, 0, stream>>>(QKVb, Vt, attnb);

    // 5. output projection (fp32 out): 128x256 tiles -> 16 x 16 = 256 blocks
    gemm_8p_kernel<128, 256, float><<<256, 512, 0, stream>>>(
        attnb, woT, out, S_LEN, DIM_, DIM_, DIM_ / 256);
}

// Round 7
// 518.282 us; speedup vs baseline: 1.0217x; 1.0217x over previous
//
#include <hip/hip_runtime.h>
#include <cstdint>
#include <cstddef>

typedef _Float16 f16_t;
typedef f16_t f16x8 __attribute__((ext_vector_type(8)));
typedef float  floatx4 __attribute__((ext_vector_type(4)));

#define S_LEN 2048
#define DIM_  4096
#define NH    32
#define NKV   8
#define HD    128
#define KV_DIM (NKV * HD)        // 1024
#define QLD   (DIM_ + 2 * KV_DIM) // 6144: fused QKV row stride

// round-to-nearest-even onto the bf16 grid, result stays fp32.
__device__ __forceinline__ float bf16r(float x) {
    uint32_t u = __float_as_uint(x);
    u = (u + 0x7fffu + ((u >> 16) & 1u)) & 0xffff0000u;
    return __uint_as_float(u);
}

// async global->LDS, 16B per lane (lane-contiguous LDS dest required)
__device__ __forceinline__ void gload_lds16(const f16_t* g, f16_t* l) {
    __builtin_amdgcn_global_load_lds(
        (const __attribute__((address_space(1))) void*)g,
        (__attribute__((address_space(3))) void*)l, 16, 0, 0);
}

// ---------------------------------------------------------------------------
// fp32 -> bf16-grid -> fp16 (lossless embed), 8 elements / thread
// ---------------------------------------------------------------------------
__global__ void f32_to_f16_kernel(const float* __restrict__ in,
                                  f16_t* __restrict__ out, int n) {
    int i = (blockIdx.x * blockDim.x + threadIdx.x) * 8;
    if (i >= n) return;
    float4 a = *(const float4*)(in + i);
    float4 b = *(const float4*)(in + i + 4);
    f16x8 o;
    o[0] = (f16_t)bf16r(a.x); o[1] = (f16_t)bf16r(a.y);
    o[2] = (f16_t)bf16r(a.z); o[3] = (f16_t)bf16r(a.w);
    o[4] = (f16_t)bf16r(b.x); o[5] = (f16_t)bf16r(b.y);
    o[6] = (f16_t)bf16r(b.z); o[7] = (f16_t)bf16r(b.w);
    *(f16x8*)(out + i) = o;
}

// ---------------------------------------------------------------------------
// all 4 weight transposes in ONE kernel (fp32 -> bf16 grid -> fp16).
// ---------------------------------------------------------------------------
__global__ void transpose_weights_kernel(const float* __restrict__ wq,
                                         const float* __restrict__ wk,
                                         const float* __restrict__ wv,
                                         const float* __restrict__ wo,
                                         f16_t* __restrict__ wqkvT,
                                         f16_t* __restrict__ woT) {
    __shared__ float tile[32][33];
    int bid = blockIdx.x;
    const float* in; f16_t* out; int C;
    if (bid < 16384)      { in = wq; out = wqkvT;                          C = 4096; }
    else if (bid < 20480) { bid -= 16384; in = wk; out = wqkvT + (size_t)4096 * 4096; C = 1024; }
    else if (bid < 24576) { bid -= 20480; in = wv; out = wqkvT + (size_t)5120 * 4096; C = 1024; }
    else                  { bid -= 24576; in = wo; out = woT;              C = 4096; }
    int gpr = C / 32;
    int bx = (bid % gpr) * 32;
    int by = (bid / gpr) * 32;
    int tx = threadIdx.x, ty = threadIdx.y;
#pragma unroll
    for (int i = 0; i < 4; i++) {
        int r = ty + i * 8;
        tile[r][tx] = in[(size_t)(by + r) * C + bx + tx];
    }
    __syncthreads();
#pragma unroll
    for (int i = 0; i < 4; i++) {
        int r = ty + i * 8;
        out[(size_t)(bx + r) * 4096 + by + tx] = (f16_t)bf16r(tile[tx][r]);
    }
}

// ---------------------------------------------------------------------------
// generic fp16 transpose with strides: in [R][C] (ldi) -> out [C][R] (ldo)
// ---------------------------------------------------------------------------
__global__ void transpose_f16_kernel(const f16_t* __restrict__ in,
                                     f16_t* __restrict__ out,
                                     int ldi, int ldo) {
    __shared__ float tile[32][33];
    int bx = blockIdx.x * 32;
    int by = blockIdx.y * 32;
    int tx = threadIdx.x, ty = threadIdx.y;
#pragma unroll
    for (int i = 0; i < 4; i++) {
        int r = ty + i * 8;
        tile[r][tx] = (float)in[(size_t)(by + r) * ldi + bx + tx];
    }
    __syncthreads();
#pragma unroll
    for (int i = 0; i < 4; i++) {
        int r = ty + i * 8;
        out[(size_t)(bx + r) * ldo + by + tx] = (f16_t)tile[tx][r];
    }
}

// ---------------------------------------------------------------------------
// RoPE in-place over QKVb cols 0..5119 (Q and K), bf16-grid cos/sin, fp32
// math; Q additionally pre-scaled by 1/sqrt(HD). grid (5, 2048), block 128.
// ---------------------------------------------------------------------------
__global__ void rope_qk_kernel(f16_t* __restrict__ QKV,
                               const float* __restrict__ fcos,
                               const float* __restrict__ fsin) {
    int c8 = (blockIdx.x * blockDim.x + threadIdx.x) * 8;
    int row = blockIdx.y;
    f16_t* p = QKV + (size_t)row * QLD + c8;
    f16x8 v = *(f16x8*)p;
    const float* cr = fcos + row * 64 + ((c8 & 127) >> 1);
    const float* sr = fsin + row * 64 + ((c8 & 127) >> 1);
    const float sc = (c8 < DIM_) ? 0.08838834764831845f : 1.0f;
#pragma unroll
    for (int u = 0; u < 4; u++) {
        float cc = bf16r(cr[u]), ss = bf16r(sr[u]);
        float re = (float)v[2 * u], im = (float)v[2 * u + 1];
        v[2 * u]     = (f16_t)((re * cc - im * ss) * sc);
        v[2 * u + 1] = (f16_t)((re * ss + im * cc) * sc);
    }
    *(f16x8*)p = v;
}

// ---------------------------------------------------------------------------
// Phase-pipelined fp16 GEMM: C[M][N] = A[M][K] @ BT[N][K]^T
// BK=64, double-buffered LDS, 8 waves (2M x 4N), 4 phases/K-tile.
// ONE barrier per phase, placed BEFORE the MFMA cluster: a wave's next-phase
// ds_reads issue right after its MFMAs and overlap other waves' MFMAs,
// completing during the barrier wait (m201 mechanism). stage(t+1) issued at
// P0 (pre-barrier). P3 drains lgkmcnt(0) (all last reads of the buffer that
// stage(t+2) overwrites) AND vmcnt(0) (own stage(t+1) writes) BEFORE its
// barrier -> past the P3 barrier: all reads done, all DMA landed. vmcnt(0)
// there drains loads issued 3 phases earlier (~free).
// Swizzle: 128B rows, cb ^= (row&7)<<4 (3 bank-group bits -> uniform,
// conflict-free), applied via inverse-swizzled global source + same XOR on
// ds_read (both-sides rule).
// ---------------------------------------------------------------------------
template <int BM, int BN, typename OutT>
__global__ __launch_bounds__(512, 2) void gemm_8p_kernel(
        const f16_t* __restrict__ A, const f16_t* __restrict__ BT,
        OutT* __restrict__ C, int M, int N, int K, int nbx) {
    constexpr int BK = 64;
    constexpr int MT = BM / 32;        // per-wave 16-row frags (BM/2 rows)
    constexpr int MH = MT / 2;         // frags per phase
    constexpr int NT = 4;              // 64 cols / 16
    constexpr int AEL = BM * BK;       // f16 elements of A tile
    constexpr int BEL = BN * BK;
    constexpr int BUF = AEL + BEL;
    constexpr int AJ = AEL * 2 / 8192; // 8KB collective issues
    constexpr int BJ = BEL * 2 / 8192;

    __shared__ f16_t lds[2 * BUF];

    const int tid  = threadIdx.x;
    const int lane = tid & 63;
    const int wave = tid >> 6;
    const int quad = lane >> 4;
    const int l16  = lane & 15;
    const int wmi  = wave >> 2;   // 0..1
    const int wni  = wave & 3;    // 0..3

    const int nwg = gridDim.x;
    const int swz = (blockIdx.x & 7) * (nwg >> 3) + (blockIdx.x >> 3);
    const int m0 = (swz / nbx) * BM;
    const int n0 = (swz % nbx) * BN;

    auto stage_all = [&](int tt) {
        f16_t* base = lds + (tt & 1) * BUF;
        const int k0 = tt * BK;
#pragma unroll
        for (int j = 0; j < AJ; j++) {
            int L = j * 8192 + tid * 16;
            int r = L >> 7;
            int c = ((L & 127) ^ ((r & 7) << 4)) >> 1;
            gload_lds16(A + (size_t)(m0 + r) * K + k0 + c, base + (L >> 1));
        }
#pragma unroll
        for (int j = 0; j < BJ; j++) {
            int L = j * 8192 + tid * 16;
            int r = L >> 7;
            int c = ((L & 127) ^ ((r & 7) << 4)) >> 1;
            gload_lds16(BT + (size_t)(n0 + r) * K + k0 + c, base + AEL + (L >> 1));
        }
    };

    floatx4 acc[MT][NT] = {};
    const int ntk = K / BK;

    // prologue: tile 0 staged + drained
    stage_all(0);
    asm volatile("s_waitcnt vmcnt(0)" ::: "memory");
    __builtin_amdgcn_s_barrier();
    __builtin_amdgcn_sched_barrier(0);

#define PHASE(mh, ks, PRESTAGE, LASTP)                                         \
    {                                                                          \
        _Pragma("unroll")                                                      \
        for (int i = 0; i < MH; i++) {                                         \
            int r_ = ((mh) * MH + i) * 16 + l16;                               \
            int cb_ = ((ks) * 64 + quad * 16) ^ ((r_ & 7) << 4);               \
            af[i] = *(const f16x8*)(Ab + r_ * 64 + (cb_ >> 1));                \
        }                                                                      \
        if ((mh) == 0) {                                                       \
            _Pragma("unroll")                                                  \
            for (int nt = 0; nt < NT; nt++) {                                  \
                int rb_ = (wni & 1) * 64 + nt * 16 + l16;                      \
                int cb_ = ((ks) * 64 + quad * 16) ^ ((rb_ & 7) << 4);          \
                bf[nt] = *(const f16x8*)(Bb + rb_ * 64 + (cb_ >> 1));          \
            }                                                                  \
        }                                                                      \
        PRESTAGE                                                               \
        if (LASTP) {                                                           \
            asm volatile("s_waitcnt lgkmcnt(0)" ::: "memory");                 \
            asm volatile("s_waitcnt vmcnt(0)" ::: "memory");                   \
        }                                                                      \
        __builtin_amdgcn_sched_barrier(0);                                     \
        __builtin_amdgcn_s_barrier();                                          \
        __builtin_amdgcn_sched_barrier(0);                                     \
        __builtin_amdgcn_s_setprio(1);                                         \
        _Pragma("unroll")                                                      \
        for (int i = 0; i < MH; i++)                                           \
            _Pragma("unroll")                                                  \
            for (int nt = 0; nt < NT; nt++)                                    \
                acc[(mh) * MH + i][nt] =                                       \
                    __builtin_amdgcn_mfma_f32_16x16x32_f16(                    \
                        af[i], bf[nt], acc[(mh) * MH + i][nt], 0, 0, 0);       \
        __builtin_amdgcn_s_setprio(0);                                         \
    }

    for (int t = 0; t < ntk; ++t) {
        const f16_t* Ab = lds + (t & 1) * BUF + wmi * (AEL / 2);
        const f16_t* Bb = lds + (t & 1) * BUF + AEL + (wni >> 1) * (BEL / 2);
        const bool pre = (t + 1 < ntk);
        f16x8 af[MH], bf[NT];

        PHASE(0, 0, if (pre) stage_all(t + 1);, false)
        PHASE(1, 0, , false)
        PHASE(0, 1, , false)
        PHASE(1, 1, , true)
    }
#undef PHASE

#pragma unroll
    for (int mt = 0; mt < MT; mt++)
#pragma unroll
        for (int nt = 0; nt < NT; nt++)
#pragma unroll
            for (int rg = 0; rg < 4; rg++) {
                int row = m0 + wmi * (BM / 2) + mt * 16 + quad * 4 + rg;
                int col = n0 + wni * 64 + nt * 16 + l16;
                C[(size_t)row * N + col] = (OutT)acc[mt][nt][rg];
            }
}

// ---------------------------------------------------------------------------
// Flash attention, causal. Q/K pre-roped (Q pre-scaled by 1/sqrt(HD)).
// (unchanged from round 5/6)
// ---------------------------------------------------------------------------
__global__ __launch_bounds__(512) void attn_kernel(
        const f16_t* __restrict__ QKV, const f16_t* __restrict__ Vt,
        f16_t* __restrict__ O) {
    constexpr int BK = 64;
    __shared__ f16_t Ks[BK * HD];
    __shared__ f16_t Vs[HD * BK];
    __shared__ f16_t Ps[8][16][72];

    const int tid  = threadIdx.x;
    const int lane = tid & 63;
    const int wave = tid >> 6;
    const int quad = lane >> 4;
    const int l16  = lane & 15;

    const int bid = blockIdx.x;
    const int h   = bid & 31;
    const int g   = bid >> 5;
    const int qt  = (g < 8) ? g : 23 - g;
    const int q0  = qt * 128;
    const int hkv = h >> 2;

    const int qrow = q0 + wave * 16 + l16;
    const f16_t* Qg = QKV + (size_t)qrow * QLD + h * HD;
    f16x8 qf[4];
#pragma unroll
    for (int c = 0; c < 4; c++) qf[c] = *(const f16x8*)(Qg + c * 32 + quad * 8);

    floatx4 o_acc[8] = {};
    floatx4 l_acc = {0.f, 0.f, 0.f, 0.f};
    float m_run[4];
#pragma unroll
    for (int i = 0; i < 4; i++) m_run[i] = -1e30f;

    f16x8 ones;
#pragma unroll
    for (int i = 0; i < 8; i++) ones[i] = (f16_t)1.0f;

    const int q_lo = q0 + wave * 16;
    const int q_hi = q_lo + 15;
    const int ntiles = q0 / BK + 2;

    const int rK = tid >> 4;
    const int cK = (((tid & 15) * 16) ^ ((rK & 7) << 4)) >> 1;
    const f16_t* pK = QKV + (size_t)rK * QLD + DIM_ + hkv * HD + cK;
    const int rV = tid >> 3;
    const int cV = (((tid & 7) * 16) ^ ((rV & 7) << 4)) >> 1;
    const f16_t* pV = Vt + (size_t)hkv * HD * S_LEN + (size_t)rV * S_LEN + cV;
    f16_t* KsD0 = Ks + tid * 8;  f16_t* KsD1 = KsD0 + 4096;
    f16_t* VsD0 = Vs + tid * 8;  f16_t* VsD1 = VsD0 + 4096;

    for (int t = 0; t < ntiles; t++) {
        const int k0 = t * BK;

        gload_lds16(pK + (size_t)k0 * QLD, KsD0);
        gload_lds16(pK + (size_t)(k0 + 32) * QLD, KsD1);
        gload_lds16(pV + k0, VsD0);
        gload_lds16(pV + k0 + (size_t)64 * S_LEN, VsD1);
        asm volatile("s_waitcnt vmcnt(0)" ::: "memory");
        __syncthreads();

        if (k0 <= q_hi) {
            floatx4 sc4[4] = {};
#pragma unroll
            for (int nt = 0; nt < 4; nt++) {
                const int r = nt * 16 + l16;
#pragma unroll
                for (int ks = 0; ks < 4; ks++) {
                    int cb = (ks * 64 + quad * 16) ^ ((r & 7) << 4);
                    f16x8 kf = *(const f16x8*)(Ks + r * 128 + (cb >> 1));
                    sc4[nt] = __builtin_amdgcn_mfma_f32_16x16x32_f16(qf[ks], kf, sc4[nt], 0, 0, 0);
                }
            }

            if ((k0 + BK - 1) > q_lo) {
#pragma unroll
                for (int nt = 0; nt < 4; nt++)
#pragma unroll
                    for (int rg = 0; rg < 4; rg++) {
                        int qg = q_lo + quad * 4 + rg;
                        int kg = k0 + nt * 16 + l16;
                        if (kg > qg) sc4[nt][rg] = -1e30f;
                    }
            }

            float m_t[4];
#pragma unroll
            for (int rg = 0; rg < 4; rg++) {
                float m = fmaxf(fmaxf(sc4[0][rg], sc4[1][rg]), fmaxf(sc4[2][rg], sc4[3][rg]));
#pragma unroll
                for (int off = 8; off >= 1; off >>= 1)
                    m = fmaxf(m, __shfl_xor(m, off, 64));
                m_t[rg] = m;
            }
            int grow = (m_t[0] > m_run[0] + 8.f) | (m_t[1] > m_run[1] + 8.f) |
                       (m_t[2] > m_run[2] + 8.f) | (m_t[3] > m_run[3] + 8.f);
            if (__any(grow)) {
                float alpha[4];
#pragma unroll
                for (int rg = 0; rg < 4; rg++) {
                    float mn = fmaxf(m_run[rg], m_t[rg]);
                    alpha[rg] = __expf(m_run[rg] - mn);
                    m_run[rg] = mn;
                }
#pragma unroll
                for (int dt = 0; dt < 8; dt++)
#pragma unroll
                    for (int rg = 0; rg < 4; rg++) o_acc[dt][rg] *= alpha[rg];
#pragma unroll
                for (int rg = 0; rg < 4; rg++) l_acc[rg] *= alpha[rg];
            }

#pragma unroll
            for (int nt = 0; nt < 4; nt++)
#pragma unroll
                for (int rg = 0; rg < 4; rg++)
                    Ps[wave][quad * 4 + rg][nt * 16 + l16] =
                        (f16_t)__expf(sc4[nt][rg] - m_run[rg]);
            asm volatile("s_waitcnt lgkmcnt(0)" ::: "memory");
            __builtin_amdgcn_sched_barrier(0);

#pragma unroll
            for (int ks = 0; ks < 2; ks++) {
                f16x8 pf = *(const f16x8*)&Ps[wave][l16][ks * 32 + quad * 8];
                l_acc = __builtin_amdgcn_mfma_f32_16x16x32_f16(pf, ones, l_acc, 0, 0, 0);
#pragma unroll
                for (int dt = 0; dt < 8; dt++) {
                    const int r = dt * 16 + l16;
                    int cb = (ks * 64 + quad * 16) ^ ((r & 7) << 4);
                    f16x8 vf = *(const f16x8*)(Vs + r * 64 + (cb >> 1));
                    o_acc[dt] = __builtin_amdgcn_mfma_f32_16x16x32_f16(pf, vf, o_acc[dt], 0, 0, 0);
                }
            }
        }
        __syncthreads();
    }

#pragma unroll
    for (int rg = 0; rg < 4; rg++) {
        float inv_l = 1.0f / l_acc[rg];
#pragma unroll
        for (int dt = 0; dt < 8; dt++) {
            int row = q0 + wave * 16 + quad * 4 + rg;
            int col = h * HD + dt * 16 + l16;
            O[(size_t)row * (NH * HD) + col] = (f16_t)(o_acc[dt][rg] * inv_l);
        }
    }
}

// ---------------------------------------------------------------------------
// launch
// ---------------------------------------------------------------------------
extern "C" void kernel_launch(void* const* d_in, const int* in_sizes, int n_in,
                              void* d_out, int out_size, void* d_ws, size_t ws_size,
                              hipStream_t stream) {
    const float* x    = (const float*)d_in[0];
    const float* wq   = (const float*)d_in[1];
    const float* wk   = (const float*)d_in[2];
    const float* wv   = (const float*)d_in[3];
    const float* wo   = (const float*)d_in[4];
    const float* fcos = (const float*)d_in[5];
    const float* fsin = (const float*)d_in[6];
    float* out = (float*)d_out;

    char* ws = (char*)d_ws;
    constexpr size_t MB = 1024 * 1024;
    f16_t* xb    = (f16_t*)(ws + 0 * MB);     // 16 MB  [2048][4096]
    f16_t* wqkvT = (f16_t*)(ws + 16 * MB);    // 48 MB  [6144][4096]
    f16_t* woT   = (f16_t*)(ws + 64 * MB);    // 32 MB  [4096][4096]
    f16_t* QKVb  = (f16_t*)(ws + 96 * MB);    // 24 MB  [2048][6144]
    f16_t* Vt    = (f16_t*)(ws + 120 * MB);   //  4 MB  [8][128][2048]
    f16_t* attnb = (f16_t*)(ws + 124 * MB);   // 16 MB  [2048][4096]

    // 1. convert x; transpose-convert all weights (bf16 grid)
    f32_to_f16_kernel<<<S_LEN * DIM_ / 8 / 256, 256, 0, stream>>>(x, xb, S_LEN * DIM_);
    transpose_weights_kernel<<<40960, dim3(32, 8), 0, stream>>>(wq, wk, wv, wo, wqkvT, woT);

    // 2. fused QKV projection: 256x256 tiles -> 8 x 24 = 192 blocks
    gemm_8p_kernel<256, 256, f16_t><<<192, 512, 0, stream>>>(
        xb, wqkvT, QKVb, S_LEN, QLD, DIM_, QLD / 256);

    // 3. RoPE Q+K in-place (Q pre-scaled); V^T transpose
    rope_qk_kernel<<<dim3(5, S_LEN), 128, 0, stream>>>(QKVb, fcos, fsin);
    transpose_f16_kernel<<<dim3(KV_DIM / 32, S_LEN / 32), dim3(32, 8), 0, stream>>>(
        QKVb + 5120, Vt, QLD, S_LEN);

    // 4. causal flash attention
    attn_kernel<<<512, 512, 0, stream>>>(QKVb, Vt, attnb);

    // 5. output projection (fp32 out): 128x256 tiles -> 16 x 16 = 256 blocks
    gemm_8p_kernel<128, 256, float><<<256, 512, 0, stream>>>(
        attnb, woT, out, S_LEN, DIM_, DIM_, DIM_ / 256);
}